// Round 2
// baseline (1132.987 us; speedup 1.0000x reference)
//
#include <hip/hip_runtime.h>
#include <stdint.h>

constexpr int SEQ    = 2048;
constexpr int DMODEL = 2048;
constexpr int NHEADS = 16;
constexpr int NKVH   = 4;
constexpr int HDIM   = 128;
constexpr int DFFN   = 8192;
constexpr int BATCH  = 2;
constexpr int MTOK   = BATCH * SEQ;   // 4096 tokens
constexpr int KKEEP  = DFFN / 2;      // 4096

typedef __bf16 bf16x8 __attribute__((ext_vector_type(8)));
typedef float  f32x4  __attribute__((ext_vector_type(4)));
typedef unsigned short u16;
typedef unsigned int   u32;

__device__ __forceinline__ u16 f2bu(float f) {  // f32 -> bf16 bits, RNE
  u32 x = __builtin_bit_cast(u32, f);
  return (u16)((x + 0x7FFFu + ((x >> 16) & 1u)) >> 16);
}
__device__ __forceinline__ float b2f(u16 u) {
  u32 v = ((u32)u) << 16;
  return __builtin_bit_cast(float, v);
}
__device__ __forceinline__ void gl_lds16(const void* g, void* l) {
  // 16B per lane; LDS dest = wave-uniform base + lane*16
  __builtin_amdgcn_global_load_lds((const __attribute__((address_space(1))) u32*)g,
                                   (__attribute__((address_space(3))) u32*)l, 16, 0, 0);
}

// ---------------- weight convert f32 -> bf16 ----------------
__global__ __launch_bounds__(256) void cvt_kernel(const float* __restrict__ in,
                                                  u16* __restrict__ out, int n) {
  int i = (blockIdx.x * 256 + threadIdx.x) * 4;
  if (i >= n) return;
  float4 v = *(const float4*)(in + i);
  uint2 pk;
  pk.x = (u32)f2bu(v.x) | ((u32)f2bu(v.y) << 16);
  pk.y = (u32)f2bu(v.z) | ((u32)f2bu(v.w) << 16);
  *(uint2*)(out + i) = pk;
}

// ---------------- RMSNorm: f32 row -> bf16 row ----------------
__global__ __launch_bounds__(256) void rmsnorm_kernel(const float* __restrict__ in,
                                                      const float* __restrict__ w,
                                                      u16* __restrict__ out) {
  const int tid = threadIdx.x;
  const size_t row = blockIdx.x;
  const float* x = in + row * DMODEL;
  float4 v0 = *(const float4*)(x + tid * 4);
  float4 v1 = *(const float4*)(x + 1024 + tid * 4);
  float s = v0.x*v0.x + v0.y*v0.y + v0.z*v0.z + v0.w*v0.w
          + v1.x*v1.x + v1.y*v1.y + v1.z*v1.z + v1.w*v1.w;
#pragma unroll
  for (int off = 1; off < 64; off <<= 1) s += __shfl_xor(s, off, 64);
  __shared__ float wsum[4];
  if ((tid & 63) == 0) wsum[tid >> 6] = s;
  __syncthreads();
  s = wsum[0] + wsum[1] + wsum[2] + wsum[3];
  const float rinv = rsqrtf(s * (1.0f / DMODEL) + 1e-6f);
  u16* o = out + row * DMODEL;
#pragma unroll
  for (int part = 0; part < 2; ++part) {
    int c = part * 1024 + tid * 4;
    float4 vv = (part == 0) ? v0 : v1;
    float4 wv = *(const float4*)(w + c);
    uint2 pk;
    pk.x = (u32)f2bu(vv.x * rinv * wv.x) | ((u32)f2bu(vv.y * rinv * wv.y) << 16);
    pk.y = (u32)f2bu(vv.z * rinv * wv.z) | ((u32)f2bu(vv.w * rinv * wv.w) << 16);
    *(uint2*)(o + c) = pk;
  }
}

// ---------------- GEMM C[M,N] = A[M,K] @ B[N,K]^T (both bf16 row-major) ----
// EPI: 0 = bf16 store, 1 = transposed V store, 2 = f32 + residual (res may
//      alias C), 3 = f32 silu
template <int EPI>
__global__ __launch_bounds__(256, 2)
void gemm_bt(const u16* __restrict__ A, const u16* __restrict__ B,
             void* __restrict__ C, const float* res,
             int M, int N, int K) {
  __shared__ u16 As[128 * 64];
  __shared__ u16 Bs[128 * 64];
  const int tid = threadIdx.x;
  const int wave = tid >> 6, lane = tid & 63;
  const int m0 = blockIdx.y * 128, n0 = blockIdx.x * 128;
  const int r_in = lane >> 3, chk = lane & 7;   // staging: 8 rows x 8 chunks / KB
  const int fk = lane >> 4, fc = lane & 15;     // MFMA fragment indices
  const int wm = (wave >> 1) * 64, wn = (wave & 1) * 64;
  f32x4 acc[4][4] = {};

  for (int kt = 0; kt < K; kt += 64) {
    __syncthreads();
#pragma unroll
    for (int i = 0; i < 4; ++i) {
      int row = wave * 32 + i * 8 + r_in;
      int gc = chk ^ (row & 7);   // pre-swizzled source, linear LDS dest
      gl_lds16(A + (size_t)(m0 + row) * K + kt + gc * 8, As + (wave * 32 + i * 8) * 64);
    }
#pragma unroll
    for (int i = 0; i < 4; ++i) {
      int row = wave * 32 + i * 8 + r_in;
      int gc = chk ^ (row & 7);
      gl_lds16(B + (size_t)(n0 + row) * K + kt + gc * 8, Bs + (wave * 32 + i * 8) * 64);
    }
    __syncthreads();
#pragma unroll
    for (int kk = 0; kk < 2; ++kk) {
      bf16x8 a[4], b[4];
#pragma unroll
      for (int i = 0; i < 4; ++i) {
        int row = wm + i * 16 + fc;
        int c = (kk * 4 + fk) ^ (row & 7);
        a[i] = *(const bf16x8*)(As + row * 64 + c * 8);
      }
#pragma unroll
      for (int j = 0; j < 4; ++j) {
        int row = wn + j * 16 + fc;
        int c = (kk * 4 + fk) ^ (row & 7);
        b[j] = *(const bf16x8*)(Bs + row * 64 + c * 8);
      }
#pragma unroll
      for (int i = 0; i < 4; ++i)
#pragma unroll
        for (int j = 0; j < 4; ++j)
          acc[i][j] = __builtin_amdgcn_mfma_f32_16x16x32_bf16(a[i], b[j], acc[i][j], 0, 0, 0);
    }
  }

  const int rb = fk * 4;  // C/D: col = lane&15, row = (lane>>4)*4 + reg
#pragma unroll
  for (int i = 0; i < 4; ++i) {
#pragma unroll
    for (int j = 0; j < 4; ++j) {
      int row = m0 + wm + i * 16 + rb;
      int col = n0 + wn + j * 16 + fc;
      f32x4 v = acc[i][j];
      if constexpr (EPI == 0) {
        u16* o = (u16*)C;
#pragma unroll
        for (int r = 0; r < 4; ++r) o[(size_t)(row + r) * N + col] = f2bu(v[r]);
      } else if constexpr (EPI == 1) {
        // vt[b][kvh][d][s] ; row = token (4 consecutive s), col = kvh*128+d
        u16* o = (u16*)C;
        int bb = row >> 11, s = row & (SEQ - 1);
        int kvh = col >> 7, d = col & (HDIM - 1);
        size_t base = (((size_t)bb * NKVH + kvh) * HDIM + d) * SEQ + s;
        uint2 pk;
        pk.x = (u32)f2bu(v[0]) | ((u32)f2bu(v[1]) << 16);
        pk.y = (u32)f2bu(v[2]) | ((u32)f2bu(v[3]) << 16);
        *(uint2*)(o + base) = pk;
      } else if constexpr (EPI == 2) {
        float* o = (float*)C;
#pragma unroll
        for (int r = 0; r < 4; ++r) {
          size_t idx = (size_t)(row + r) * N + col;
          float rv = res[idx];
          o[idx] = v[r] + rv;
        }
      } else {  // EPI == 3 : silu
        float* o = (float*)C;
#pragma unroll
        for (int r = 0; r < 4; ++r) {
          float g = v[r];
          o[(size_t)(row + r) * N + col] = g / (1.0f + __expf(-g));
        }
      }
    }
  }
}

// ---------------- flash attention (causal GQA) ----------------
// grid: (SEQ/64, NHEADS, BATCH). 4 waves/block; wave w owns q rows [q0+16w, q0+16w+16)
__global__ __launch_bounds__(256, 2)
void attn_kernel(const u16* __restrict__ Q, const u16* __restrict__ Kb,
                 const u16* __restrict__ Vt, u16* __restrict__ O) {
  __shared__ u16 Ks[32 * 128];    // [kv][d] swizzled
  __shared__ u16 Vs[128 * 32];    // [d][kv] swizzled
  __shared__ u16 Ps[4][16 * 32];  // per-wave P, swizzled
  const int tid = threadIdx.x, wave = tid >> 6, lane = tid & 63;
  const int qt = blockIdx.x, h = blockIdx.y, b = blockIdx.z;
  const int kvh = h >> 2;
  const int q0 = qt * 64, qw = q0 + wave * 16;
  const int fk = lane >> 4, fc = lane & 15;
  const float SC = 0.08838834764831845f;  // 1/sqrt(128)

  bf16x8 qf[4];
  {
    const u16* qp = Q + ((size_t)(b * SEQ + qw + fc)) * DMODEL + h * HDIM + fk * 8;
#pragma unroll
    for (int f = 0; f < 4; ++f) qf[f] = *(const bf16x8*)(qp + f * 32);
  }
  f32x4 oacc[8] = {};
  float m_run[4] = {-1e30f, -1e30f, -1e30f, -1e30f};
  float l_run[4] = {0.f, 0.f, 0.f, 0.f};
  const int nt = (q0 + 64) / 32;
  const int kr = lane >> 4, kc = lane & 15;  // K staging: 4 rows x 16 chunks
  const int vr = lane >> 2, vc = lane & 3;   // V staging: 16 rows x 4 chunks

  for (int t = 0; t < nt; ++t) {
    const int k0 = t * 32;
    __syncthreads();
#pragma unroll
    for (int ii = 0; ii < 2; ++ii) {
      int issue = wave * 2 + ii;
      {  // K tile: 32 rows x 256B
        int row = issue * 4 + kr;
        int gc = kc ^ (row & 7);
        gl_lds16(Kb + ((size_t)(b * SEQ + k0 + row)) * (NKVH * HDIM) + kvh * HDIM + gc * 8,
                 Ks + issue * 4 * 128);
      }
      {  // V tile: 128 d-rows x 64B
        int row = issue * 16 + vr;
        int gc = vc ^ ((row >> 1) & 3);
        gl_lds16(Vt + (((size_t)b * NKVH + kvh) * HDIM + row) * SEQ + k0 + gc * 8,
                 Vs + issue * 16 * 32);
      }
    }
    __syncthreads();
    if (k0 <= qw + 15) {
      f32x4 sf[2] = {};
#pragma unroll
      for (int sb = 0; sb < 2; ++sb) {
#pragma unroll
        for (int f = 0; f < 4; ++f) {
          int kvr = sb * 16 + fc;
          int c = (f * 4 + fk) ^ (kvr & 7);
          bf16x8 kf = *(const bf16x8*)(Ks + kvr * 128 + c * 8);
          sf[sb] = __builtin_amdgcn_mfma_f32_16x16x32_bf16(qf[f], kf, sf[sb], 0, 0, 0);
        }
      }
#pragma unroll
      for (int r = 0; r < 4; ++r) {
        const int qrow = qw + fk * 4 + r;
        float s0 = sf[0][r] * SC, s1 = sf[1][r] * SC;
        if (k0 + fc > qrow) s0 = -1e30f;
        if (k0 + 16 + fc > qrow) s1 = -1e30f;
        float mx = fmaxf(s0, s1);
#pragma unroll
        for (int off = 1; off < 16; off <<= 1) mx = fmaxf(mx, __shfl_xor(mx, off, 64));
        float mnew = fmaxf(m_run[r], mx);
        float p0 = __expf(s0 - mnew), p1 = __expf(s1 - mnew);
        float rs = p0 + p1;
#pragma unroll
        for (int off = 1; off < 16; off <<= 1) rs += __shfl_xor(rs, off, 64);
        float alpha = __expf(m_run[r] - mnew);
        m_run[r] = mnew;
        l_run[r] = l_run[r] * alpha + rs;
#pragma unroll
        for (int f = 0; f < 8; ++f) oacc[f][r] *= alpha;
        const int prow = fk * 4 + r;
        const int key = (prow >> 1) & 3;
        Ps[wave][prow * 32 + ((((fc >> 3)) ^ key) << 3) + (fc & 7)] = f2bu(p0);
        Ps[wave][prow * 32 + ((((fc >> 3) + 2) ^ key) << 3) + (fc & 7)] = f2bu(p1);
      }
      bf16x8 pf = *(const bf16x8*)(&Ps[wave][fc * 32 + ((fk ^ ((fc >> 1) & 3)) << 3)]);
#pragma unroll
      for (int f = 0; f < 8; ++f) {
        int d = f * 16 + fc;
        int c = fk ^ ((d >> 1) & 3);
        bf16x8 vf = *(const bf16x8*)(Vs + d * 32 + c * 8);
        oacc[f] = __builtin_amdgcn_mfma_f32_16x16x32_bf16(pf, vf, oacc[f], 0, 0, 0);
      }
    }
  }
  u16* op = O + ((size_t)(b * SEQ + qw + fk * 4)) * DMODEL + h * HDIM + fc;
#pragma unroll
  for (int r = 0; r < 4; ++r) {
    float inv = 1.0f / l_run[r];
#pragma unroll
    for (int f = 0; f < 8; ++f) op[(size_t)r * DMODEL + f * 16] = f2bu(oacc[f][r] * inv);
  }
}

// ---------------- top-k (exact radix select) + gate*up, in-place over up ---
__global__ __launch_bounds__(256)
void topk_kernel(const float* __restrict__ gate, u16* __restrict__ upact) {
  __shared__ u32 sabs[DFFN];       // silu(gate) f32 bits
  __shared__ u32 hist[4][256];
  __shared__ u32 ss[257];
  __shared__ u32 sh_prefix, sh_rem;
  const int tid = threadIdx.x, wave = tid >> 6;
  const size_t row = blockIdx.x;
  const float* g = gate + row * DFFN;
  for (int it = 0; it < 4; ++it) {
    int e = it * 2048 + tid * 8;
    float4 a = *(const float4*)(g + e);
    float4 b = *(const float4*)(g + e + 4);
    sabs[e + 0] = __builtin_bit_cast(u32, a.x);
    sabs[e + 1] = __builtin_bit_cast(u32, a.y);
    sabs[e + 2] = __builtin_bit_cast(u32, a.z);
    sabs[e + 3] = __builtin_bit_cast(u32, a.w);
    sabs[e + 4] = __builtin_bit_cast(u32, b.x);
    sabs[e + 5] = __builtin_bit_cast(u32, b.y);
    sabs[e + 6] = __builtin_bit_cast(u32, b.z);
    sabs[e + 7] = __builtin_bit_cast(u32, b.w);
  }
  if (tid == 0) { sh_prefix = 0; sh_rem = KKEEP; }
  __syncthreads();
  for (int pass = 0; pass < 4; ++pass) {
    const int p = 24 - pass * 8;
    const u32 mask_hi = (pass == 0) ? 0u : (0xFFFFFFFFu << (p + 8));
    for (int i = tid; i < 1024; i += 256) ((u32*)hist)[i] = 0;
    __syncthreads();
    const u32 prefix = sh_prefix, rem = sh_rem;
    for (int it = 0; it < 4; ++it) {
      int e = it * 2048 + tid * 8;
#pragma unroll
      for (int j = 0; j < 8; ++j) {
        u32 mg = sabs[e + j] & 0x7FFFFFFFu;
        if ((mg & mask_hi) == (prefix & mask_hi))
          atomicAdd(&hist[wave][(mg >> p) & 0xFF], 1u);
      }
    }
    __syncthreads();
    ss[tid] = hist[0][tid] + hist[1][tid] + hist[2][tid] + hist[3][tid];
    if (tid == 0) ss[256] = 0;
    __syncthreads();
    for (int off = 1; off < 256; off <<= 1) {
      u32 v = (tid + off < 256) ? ss[tid + off] : 0u;
      __syncthreads();
      ss[tid] += v;
      __syncthreads();
    }
    if (ss[tid] >= rem && ss[tid + 1] < rem) {
      sh_prefix = prefix | ((u32)tid << p);
      sh_rem = rem - ss[tid + 1];
    }
    __syncthreads();
  }
  const u32 thr = sh_prefix;
  u16* ua = upact + row * DFFN;
  for (int it = 0; it < 4; ++it) {
    int e = it * 2048 + tid * 8;
    uint4 uv = *(const uint4*)(ua + e);
    const u16* up16 = (const u16*)&uv;
    u16 outp[8];
#pragma unroll
    for (int j = 0; j < 8; ++j) {
      u32 bits = sabs[e + j];
      u32 mg = bits & 0x7FFFFFFFu;
      float gg = __builtin_bit_cast(float, bits);
      float prod = (mg >= thr) ? gg * b2f(up16[j]) : 0.0f;
      outp[j] = f2bu(prod);
    }
    uint4 ov;
    ov.x = (u32)outp[0] | ((u32)outp[1] << 16);
    ov.y = (u32)outp[2] | ((u32)outp[3] << 16);
    ov.z = (u32)outp[4] | ((u32)outp[5] << 16);
    ov.w = (u32)outp[6] | ((u32)outp[7] << 16);
    *(uint4*)(ua + e) = ov;
  }
}

// ---------------- launcher ----------------
extern "C" void kernel_launch(void* const* d_in, const int* in_sizes, int n_in,
                              void* d_out, int out_size, void* d_ws, size_t ws_size,
                              hipStream_t stream) {
  const float* hidden = (const float*)d_in[0];
  const float* wq = (const float*)d_in[1];
  const float* wk = (const float*)d_in[2];
  const float* wv = (const float*)d_in[3];
  const float* wo = (const float*)d_in[4];
  const float* ln1 = (const float*)d_in[5];
  const float* ln2 = (const float*)d_in[6];
  const float* wg = (const float*)d_in[7];
  const float* wu = (const float*)d_in[8];
  const float* wd = (const float*)d_in[9];
  float* out = (float*)d_out;
  (void)in_sizes; (void)n_in; (void)out_size;

  // ---- workspace layout (lifetime-aliased, ~196 MB total) ----
  size_t off = 0;
  auto alloc = [&](size_t n) { char* r = (char*)d_ws + off; off += (n + 255) & ~(size_t)255; return r; };
  u16* wq_b = (u16*)alloc((size_t)DMODEL * DMODEL * 2);      // 8 MB
  u16* wk_b = (u16*)alloc((size_t)NKVH * HDIM * DMODEL * 2); // 2 MB
  u16* wv_b = (u16*)alloc((size_t)NKVH * HDIM * DMODEL * 2); // 2 MB
  u16* wo_b = (u16*)alloc((size_t)DMODEL * DMODEL * 2);      // 8 MB
  u16* wg_b = (u16*)alloc((size_t)DFFN * DMODEL * 2);        // 32 MB
  u16* tok  = (u16*)alloc((size_t)MTOK * DMODEL * 2);        // 16 MB: x -> o -> y
  u16* upb  = (u16*)alloc((size_t)MTOK * DFFN * 2);          // 64 MB
  char* S   = alloc((size_t)(MTOK / 2) * DFFN * 4);          // 64 MB shared region
  // phase 1 of S: qb(16) kb(4) vtb(4) wu_b(32)
  u16* qb   = (u16*)S;
  u16* kb   = (u16*)(S + (size_t)MTOK * DMODEL * 2);
  u16* vtb  = (u16*)(S + (size_t)MTOK * DMODEL * 2 + (size_t)MTOK * NKVH * HDIM * 2);
  u16* wu_b = (u16*)(S + (size_t)MTOK * DMODEL * 2 + 2 * (size_t)MTOK * NKVH * HDIM * 2);
  // phase 2 of S: gate half (f32, 2048 x 8192)
  float* gateh = (float*)S;
  // phase 3 of S: wd_b (32 MB)
  u16* wd_b = (u16*)S;
  const size_t needed = off;
  if (ws_size < needed) return;  // clean fast-fail (diagnostic) instead of OOB hang

  auto cvt = [&](const float* src, u16* dst, size_t n) {
    cvt_kernel<<<dim3((unsigned)(n / 1024)), 256, 0, stream>>>(src, dst, (int)n);
  };
  cvt(wq, wq_b, (size_t)DMODEL * DMODEL);
  cvt(wk, wk_b, (size_t)NKVH * HDIM * DMODEL);
  cvt(wv, wv_b, (size_t)NKVH * HDIM * DMODEL);
  cvt(wo, wo_b, (size_t)DMODEL * DMODEL);
  cvt(wg, wg_b, (size_t)DFFN * DMODEL);
  cvt(wu, wu_b, (size_t)DFFN * DMODEL);

  // x = rmsnorm(hidden, ln1)
  rmsnorm_kernel<<<MTOK, 256, 0, stream>>>(hidden, ln1, tok);

  gemm_bt<0><<<dim3(DMODEL / 128, MTOK / 128), 256, 0, stream>>>(
      tok, wq_b, qb, nullptr, MTOK, DMODEL, DMODEL);
  gemm_bt<0><<<dim3(NKVH * HDIM / 128, MTOK / 128), 256, 0, stream>>>(
      tok, wk_b, kb, nullptr, MTOK, NKVH * HDIM, DMODEL);
  gemm_bt<1><<<dim3(NKVH * HDIM / 128, MTOK / 128), 256, 0, stream>>>(
      tok, wv_b, vtb, nullptr, MTOK, NKVH * HDIM, DMODEL);

  // o -> tok (x dead)
  attn_kernel<<<dim3(SEQ / 64, NHEADS, BATCH), 256, 0, stream>>>(qb, kb, vtb, tok);

  // h = hidden + o @ wo^T   -> stored in d_out
  gemm_bt<2><<<dim3(DMODEL / 128, MTOK / 128), 256, 0, stream>>>(
      tok, wo_b, out, hidden, MTOK, DMODEL, DMODEL);

  // y = rmsnorm(h, ln2) -> tok (o dead)
  rmsnorm_kernel<<<MTOK, 256, 0, stream>>>(out, ln2, tok);

  // up = y @ wu^T (bf16) — must complete before S is reused for gate halves
  gemm_bt<0><<<dim3(DFFN / 128, MTOK / 128), 256, 0, stream>>>(
      tok, wu_b, upb, nullptr, MTOK, DFFN, DMODEL);

  // gate halves: silu(y @ wg^T) f32 -> topk+multiply in-place into upb
  for (int half = 0; half < 2; ++half) {
    const u16* yh = tok + (size_t)half * (MTOK / 2) * DMODEL;
    u16* uph = upb + (size_t)half * (MTOK / 2) * DFFN;
    gemm_bt<3><<<dim3(DFFN / 128, (MTOK / 2) / 128), 256, 0, stream>>>(
        yh, wg_b, gateh, nullptr, MTOK / 2, DFFN, DMODEL);
    topk_kernel<<<MTOK / 2, 256, 0, stream>>>(gateh, uph);
  }

  // wd -> bf16 (into S, gate halves dead)
  cvt(wd, wd_b, (size_t)DMODEL * DFFN);

  // out = h + act @ wd^T  (in-place residual over d_out)
  gemm_bt<2><<<dim3(DMODEL / 128, MTOK / 128), 256, 0, stream>>>(
      upb, wd_b, out, out, MTOK, DMODEL, DFFN);
}

// Round 3
// 1085.892 us; speedup vs baseline: 1.0434x; 1.0434x over previous
//
#include <hip/hip_runtime.h>
#include <stdint.h>

constexpr int SEQ    = 2048;
constexpr int DMODEL = 2048;
constexpr int NHEADS = 16;
constexpr int NKVH   = 4;
constexpr int HDIM   = 128;
constexpr int DFFN   = 8192;
constexpr int BATCH  = 2;
constexpr int MTOK   = BATCH * SEQ;   // 4096 tokens
constexpr int KKEEP  = DFFN / 2;      // 4096

typedef __bf16 bf16x8 __attribute__((ext_vector_type(8)));
typedef float  f32x4  __attribute__((ext_vector_type(4)));
typedef float  f32x16 __attribute__((ext_vector_type(16)));
typedef unsigned short u16;
typedef unsigned int   u32;

__device__ __forceinline__ u16 f2bu(float f) {  // f32 -> bf16 bits, RNE
  u32 x = __builtin_bit_cast(u32, f);
  return (u16)((x + 0x7FFFu + ((x >> 16) & 1u)) >> 16);
}
__device__ __forceinline__ float b2f(u16 u) {
  u32 v = ((u32)u) << 16;
  return __builtin_bit_cast(float, v);
}
__device__ __forceinline__ void gl_lds16(const void* g, void* l) {
  // 16B per lane; LDS dest = wave-uniform base + lane*16
  __builtin_amdgcn_global_load_lds((const __attribute__((address_space(1))) u32*)g,
                                   (__attribute__((address_space(3))) u32*)l, 16, 0, 0);
}

// ---------------- weight convert f32 -> bf16 ----------------
__global__ __launch_bounds__(256) void cvt_kernel(const float* __restrict__ in,
                                                  u16* __restrict__ out, int n) {
  int i = (blockIdx.x * 256 + threadIdx.x) * 4;
  if (i >= n) return;
  float4 v = *(const float4*)(in + i);
  uint2 pk;
  pk.x = (u32)f2bu(v.x) | ((u32)f2bu(v.y) << 16);
  pk.y = (u32)f2bu(v.z) | ((u32)f2bu(v.w) << 16);
  *(uint2*)(out + i) = pk;
}

// ---------------- RMSNorm: f32 row -> bf16 row ----------------
__global__ __launch_bounds__(256) void rmsnorm_kernel(const float* __restrict__ in,
                                                      const float* __restrict__ w,
                                                      u16* __restrict__ out) {
  const int tid = threadIdx.x;
  const size_t row = blockIdx.x;
  const float* x = in + row * DMODEL;
  float4 v0 = *(const float4*)(x + tid * 4);
  float4 v1 = *(const float4*)(x + 1024 + tid * 4);
  float s = v0.x*v0.x + v0.y*v0.y + v0.z*v0.z + v0.w*v0.w
          + v1.x*v1.x + v1.y*v1.y + v1.z*v1.z + v1.w*v1.w;
#pragma unroll
  for (int off = 1; off < 64; off <<= 1) s += __shfl_xor(s, off, 64);
  __shared__ float wsum[4];
  if ((tid & 63) == 0) wsum[tid >> 6] = s;
  __syncthreads();
  s = wsum[0] + wsum[1] + wsum[2] + wsum[3];
  const float rinv = rsqrtf(s * (1.0f / DMODEL) + 1e-6f);
  u16* o = out + row * DMODEL;
#pragma unroll
  for (int part = 0; part < 2; ++part) {
    int c = part * 1024 + tid * 4;
    float4 vv = (part == 0) ? v0 : v1;
    float4 wv = *(const float4*)(w + c);
    uint2 pk;
    pk.x = (u32)f2bu(vv.x * rinv * wv.x) | ((u32)f2bu(vv.y * rinv * wv.y) << 16);
    pk.y = (u32)f2bu(vv.z * rinv * wv.z) | ((u32)f2bu(vv.w * rinv * wv.w) << 16);
    *(uint2*)(o + c) = pk;
  }
}

// ---------------- GEMM C[M,N] = A[M,K] @ B[N,K]^T (both bf16 row-major) ----
// EPI: 0 = bf16 store, 1 = transposed V store, 2 = f32 + residual (res may
//      alias C), 3 = f32 silu
template <int EPI>
__global__ __launch_bounds__(256, 2)
void gemm_bt(const u16* __restrict__ A, const u16* __restrict__ B,
             void* __restrict__ C, const float* res,
             int M, int N, int K) {
  __shared__ u16 As[128 * 64];
  __shared__ u16 Bs[128 * 64];
  const int tid = threadIdx.x;
  const int wave = tid >> 6, lane = tid & 63;
  // XCD-aware block swizzle (T1); all grids have nwg % 8 == 0
  const int nwg = gridDim.x * gridDim.y;
  const int lin = blockIdx.y * gridDim.x + blockIdx.x;
  const int swz = (lin & 7) * (nwg >> 3) + (lin >> 3);
  const int m0 = (swz / gridDim.x) * 128, n0 = (swz % gridDim.x) * 128;
  const int r_in = lane >> 3, chk = lane & 7;   // staging: 8 rows x 8 chunks / KB
  const int fk = lane >> 4, fc = lane & 15;     // MFMA fragment indices
  const int wm = (wave >> 1) * 64, wn = (wave & 1) * 64;
  f32x4 acc[4][4] = {};

  for (int kt = 0; kt < K; kt += 64) {
    __syncthreads();
#pragma unroll
    for (int i = 0; i < 4; ++i) {
      int row = wave * 32 + i * 8 + r_in;
      int gc = chk ^ (row & 7);   // pre-swizzled source, linear LDS dest
      gl_lds16(A + (size_t)(m0 + row) * K + kt + gc * 8, As + (wave * 32 + i * 8) * 64);
    }
#pragma unroll
    for (int i = 0; i < 4; ++i) {
      int row = wave * 32 + i * 8 + r_in;
      int gc = chk ^ (row & 7);
      gl_lds16(B + (size_t)(n0 + row) * K + kt + gc * 8, Bs + (wave * 32 + i * 8) * 64);
    }
    __syncthreads();
#pragma unroll
    for (int kk = 0; kk < 2; ++kk) {
      bf16x8 a[4], b[4];
#pragma unroll
      for (int i = 0; i < 4; ++i) {
        int row = wm + i * 16 + fc;
        int c = (kk * 4 + fk) ^ (row & 7);
        a[i] = *(const bf16x8*)(As + row * 64 + c * 8);
      }
#pragma unroll
      for (int j = 0; j < 4; ++j) {
        int row = wn + j * 16 + fc;
        int c = (kk * 4 + fk) ^ (row & 7);
        b[j] = *(const bf16x8*)(Bs + row * 64 + c * 8);
      }
#pragma unroll
      for (int i = 0; i < 4; ++i)
#pragma unroll
        for (int j = 0; j < 4; ++j)
          acc[i][j] = __builtin_amdgcn_mfma_f32_16x16x32_bf16(a[i], b[j], acc[i][j], 0, 0, 0);
    }
  }

  const int rb = fk * 4;  // C/D: col = lane&15, row = (lane>>4)*4 + reg
#pragma unroll
  for (int i = 0; i < 4; ++i) {
#pragma unroll
    for (int j = 0; j < 4; ++j) {
      int row = m0 + wm + i * 16 + rb;
      int col = n0 + wn + j * 16 + fc;
      f32x4 v = acc[i][j];
      if constexpr (EPI == 0) {
        u16* o = (u16*)C;
#pragma unroll
        for (int r = 0; r < 4; ++r) o[(size_t)(row + r) * N + col] = f2bu(v[r]);
      } else if constexpr (EPI == 1) {
        // vt[b][kvh][d][s] ; row = token (4 consecutive s), col = kvh*128+d
        u16* o = (u16*)C;
        int bb = row >> 11, s = row & (SEQ - 1);
        int kvh = col >> 7, d = col & (HDIM - 1);
        size_t base = (((size_t)bb * NKVH + kvh) * HDIM + d) * SEQ + s;
        uint2 pk;
        pk.x = (u32)f2bu(v[0]) | ((u32)f2bu(v[1]) << 16);
        pk.y = (u32)f2bu(v[2]) | ((u32)f2bu(v[3]) << 16);
        *(uint2*)(o + base) = pk;
      } else if constexpr (EPI == 2) {
        float* o = (float*)C;
#pragma unroll
        for (int r = 0; r < 4; ++r) {
          size_t idx = (size_t)(row + r) * N + col;
          float rv = res[idx];
          o[idx] = v[r] + rv;
        }
      } else {  // EPI == 3 : silu
        float* o = (float*)C;
#pragma unroll
        for (int r = 0; r < 4; ++r) {
          float g = v[r];
          o[(size_t)(row + r) * N + col] = g / (1.0f + __expf(-g));
        }
      }
    }
  }
}

// ---------------- flash attention (causal GQA, swapped-QK, 32x32 MFMA) -----
// block = 4 waves; wave w owns q-strip [bx*128 + 32w, +32). KVBLK=32.
// S^T = mfma(K, Q): lane owns q-col (lane&31); 16 kv-scores per lane.
__global__ __launch_bounds__(256, 2)
void attn_kernel(const u16* __restrict__ Q, const u16* __restrict__ Kb,
                 const u16* __restrict__ Vt, u16* __restrict__ O) {
  __shared__ u16 Ksh[2 * 32 * 128];   // [buf][kv][d], chunk^(kv&15) swizzle
  __shared__ u16 Vsh[2 * 128 * 32];   // [buf][d][kv], chunk^((d>>1)&3) swizzle
  const int tid = threadIdx.x, wave = tid >> 6, lane = tid & 63;
  const int half = lane >> 5, l31 = lane & 31;
  // XCD swizzle: dispatch d -> logical block (d%8)*64 + d/8 so each XCD
  // owns exactly one (b,kvh) -> its 1MB K+V stays in that XCD's L2.
  const int d_lin = blockIdx.x + gridDim.x * (blockIdx.y + gridDim.y * blockIdx.z);
  const int lin = (d_lin & 7) * 64 + (d_lin >> 3);
  const int bx = lin & 15, h = (lin >> 4) & 15, b = lin >> 8;
  const int kvh = h >> 2;
  const int qw = bx * 128 + wave * 32;
  const float SC = 0.08838834764831845f;  // 1/sqrt(128)
  const int ntb = bx * 4 + 4;             // staged tiles per block
  const int nmy = bx * 4 + wave;          // last tile index this wave computes

  // persistent Q fragments: qf[s] lane: Q[qw + l31][s*16 + half*8 + j]
  bf16x8 qf[8];
  {
    const u16* qp = Q + ((size_t)(b * SEQ + qw + l31)) * DMODEL + h * HDIM + half * 8;
#pragma unroll
    for (int s = 0; s < 8; ++s) qf[s] = *(const bf16x8*)(qp + s * 16);
  }
  f32x16 oacc[4] = {};
  float m_run = -1e30f, l_run = 0.0f;
  const size_t vbase = ((size_t)(b * NKVH + kvh)) * HDIM * SEQ;
  const u16* kbase = Kb + (size_t)b * SEQ * (NKVH * HDIM) + kvh * HDIM;

  auto stage = [&](int bi, int k0) {
    u16* Kd = Ksh + bi * 4096;
    u16* Vd = Vsh + bi * 4096;
#pragma unroll
    for (int ii = 0; ii < 2; ++ii) {
      int inst = wave * 2 + ii;
      {  // K: instr covers kv rows 4*inst..+3, 256B each
        int row = inst * 4 + (lane >> 4);
        int c = (lane & 15) ^ (row & 15);
        gl_lds16(kbase + (size_t)(k0 + row) * (NKVH * HDIM) + c * 8, Kd + inst * 512);
      }
      {  // V^T: instr covers d rows 16*inst..+15, 64B each
        int row = inst * 16 + (lane >> 2);
        int c = (lane & 3) ^ ((row >> 1) & 3);
        gl_lds16(Vt + vbase + (size_t)row * SEQ + k0 + c * 8, Vd + inst * 512);
      }
    }
  };

  stage(0, 0);
  __syncthreads();

  for (int t = 0; t < ntb; ++t) {
    if (t + 1 < ntb) stage((t + 1) & 1, (t + 1) * 32);
    if (t <= nmy) {
      const u16* Kd = Ksh + (t & 1) * 4096;
      const u16* Vd = Vsh + (t & 1) * 4096;
      // ---- S^T[kv][q] over d=128 ----
      f32x16 st = {};
#pragma unroll
      for (int s = 0; s < 8; ++s) {
        int c = (half + 2 * s) ^ (l31 & 15);
        bf16x8 kf = *(const bf16x8*)(Kd + l31 * 128 + c * 8);
        st = __builtin_amdgcn_mfma_f32_32x32x16_bf16(kf, qf[s], st, 0, 0, 0);
      }
      // ---- softmax (lane owns q = qw + l31; kv(r) = (r&3)+8*(r>>2)+4*half)
      const bool diag = (t * 32 == qw);
      float sv[16];
#pragma unroll
      for (int r = 0; r < 16; ++r) {
        float x = st[r] * SC;
        if (diag) {
          int kvl = (r & 3) + 8 * (r >> 2) + 4 * half;
          if (kvl > l31) x = -1e30f;
        }
        sv[r] = x;
      }
      float mx = sv[0];
#pragma unroll
      for (int r = 1; r < 16; ++r) mx = fmaxf(mx, sv[r]);
      mx = fmaxf(mx, __shfl_xor(mx, 32, 64));
      if (__any(mx > m_run + 4.0f)) {   // defer-max (exact): rescale rarely
        float mnew = fmaxf(m_run, mx);
        float alpha = __expf(m_run - mnew);
        m_run = mnew;
        l_run *= alpha;
#pragma unroll
        for (int r = 0; r < 16; ++r) {
          float ar = __shfl(alpha, (r & 3) + 8 * (r >> 2) + 4 * half, 64);
#pragma unroll
          for (int dt = 0; dt < 4; ++dt) oacc[dt][r] *= ar;
        }
      }
      float p[16];
      float rs = 0.0f;
#pragma unroll
      for (int r = 0; r < 16; ++r) { p[r] = __expf(sv[r] - m_run); rs += p[r]; }
      rs += __shfl_xor(rs, 32, 64);
      l_run += rs;
      // ---- P -> bf16 A-fragments via half-swap ----
      u32 c01 = (u32)f2bu(p[0])  | ((u32)f2bu(p[1])  << 16);
      u32 c23 = (u32)f2bu(p[2])  | ((u32)f2bu(p[3])  << 16);
      u32 c45 = (u32)f2bu(p[4])  | ((u32)f2bu(p[5])  << 16);
      u32 c67 = (u32)f2bu(p[6])  | ((u32)f2bu(p[7])  << 16);
      u32 c89 = (u32)f2bu(p[8])  | ((u32)f2bu(p[9])  << 16);
      u32 cAB = (u32)f2bu(p[10]) | ((u32)f2bu(p[11]) << 16);
      u32 cCD = (u32)f2bu(p[12]) | ((u32)f2bu(p[13]) << 16);
      u32 cEF = (u32)f2bu(p[14]) | ((u32)f2bu(p[15]) << 16);
      u32 paw[2][4];
      {
        u32 sA = __shfl_xor(c01, 32, 64), sB = __shfl_xor(c23, 32, 64);
        u32 sC = __shfl_xor(c45, 32, 64), sD = __shfl_xor(c67, 32, 64);
        paw[0][0] = half ? sC : c01;  paw[0][1] = half ? sD : c23;
        paw[0][2] = half ? c45 : sA;  paw[0][3] = half ? c67 : sB;
      }
      {
        u32 sA = __shfl_xor(c89, 32, 64), sB = __shfl_xor(cAB, 32, 64);
        u32 sC = __shfl_xor(cCD, 32, 64), sD = __shfl_xor(cEF, 32, 64);
        paw[1][0] = half ? sC : c89;  paw[1][1] = half ? sD : cAB;
        paw[1][2] = half ? cCD : sA;  paw[1][3] = half ? cEF : sB;
      }
      // ---- PV: oacc[dt][q-rows] += P[q][kv] * V[kv][d] ----
#pragma unroll
      for (int ks = 0; ks < 2; ++ks) {
        bf16x8 paf = __builtin_bit_cast(bf16x8, *(uint4*)&paw[ks][0]);
#pragma unroll
        for (int dt = 0; dt < 4; ++dt) {
          int row = dt * 32 + l31;
          int c = (half + 2 * ks) ^ ((row >> 1) & 3);
          bf16x8 vf = *(const bf16x8*)(Vd + row * 32 + c * 8);
          oacc[dt] = __builtin_amdgcn_mfma_f32_32x32x16_bf16(paf, vf, oacc[dt], 0, 0, 0);
        }
      }
    }
    __syncthreads();
  }

  // ---- epilogue: O[q][d] / l[q] ----
  float rinv = 1.0f / l_run;
  u16* ob = O + ((size_t)(b * SEQ + qw)) * DMODEL + h * HDIM + l31;
#pragma unroll
  for (int r = 0; r < 16; ++r) {
    int qr = (r & 3) + 8 * (r >> 2) + 4 * half;
    float ir = __shfl(rinv, qr, 64);
#pragma unroll
    for (int dt = 0; dt < 4; ++dt)
      ob[(size_t)qr * DMODEL + dt * 32] = f2bu(oacc[dt][r] * ir);
  }
}

// ---------------- top-k (exact radix select) + gate*up, in-place over up ---
__global__ __launch_bounds__(256)
void topk_kernel(const float* __restrict__ gate, u16* __restrict__ upact) {
  __shared__ u32 sabs[DFFN];       // silu(gate) f32 bits
  __shared__ u32 hist[4][256];
  __shared__ u32 ss[257];
  __shared__ u32 sh_prefix, sh_rem;
  const int tid = threadIdx.x, wave = tid >> 6;
  const size_t row = blockIdx.x;
  const float* g = gate + row * DFFN;
  for (int it = 0; it < 4; ++it) {
    int e = it * 2048 + tid * 8;
    float4 a = *(const float4*)(g + e);
    float4 b = *(const float4*)(g + e + 4);
    sabs[e + 0] = __builtin_bit_cast(u32, a.x);
    sabs[e + 1] = __builtin_bit_cast(u32, a.y);
    sabs[e + 2] = __builtin_bit_cast(u32, a.z);
    sabs[e + 3] = __builtin_bit_cast(u32, a.w);
    sabs[e + 4] = __builtin_bit_cast(u32, b.x);
    sabs[e + 5] = __builtin_bit_cast(u32, b.y);
    sabs[e + 6] = __builtin_bit_cast(u32, b.z);
    sabs[e + 7] = __builtin_bit_cast(u32, b.w);
  }
  if (tid == 0) { sh_prefix = 0; sh_rem = KKEEP; }
  __syncthreads();
  for (int pass = 0; pass < 4; ++pass) {
    const int p = 24 - pass * 8;
    const u32 mask_hi = (pass == 0) ? 0u : (0xFFFFFFFFu << (p + 8));
    for (int i = tid; i < 1024; i += 256) ((u32*)hist)[i] = 0;
    __syncthreads();
    const u32 prefix = sh_prefix, rem = sh_rem;
    for (int it = 0; it < 4; ++it) {
      int e = it * 2048 + tid * 8;
#pragma unroll
      for (int j = 0; j < 8; ++j) {
        u32 mg = sabs[e + j] & 0x7FFFFFFFu;
        if ((mg & mask_hi) == (prefix & mask_hi))
          atomicAdd(&hist[wave][(mg >> p) & 0xFF], 1u);
      }
    }
    __syncthreads();
    ss[tid] = hist[0][tid] + hist[1][tid] + hist[2][tid] + hist[3][tid];
    if (tid == 0) ss[256] = 0;
    __syncthreads();
    for (int off = 1; off < 256; off <<= 1) {
      u32 v = (tid + off < 256) ? ss[tid + off] : 0u;
      __syncthreads();
      ss[tid] += v;
      __syncthreads();
    }
    if (ss[tid] >= rem && ss[tid + 1] < rem) {
      sh_prefix = prefix | ((u32)tid << p);
      sh_rem = rem - ss[tid + 1];
    }
    __syncthreads();
  }
  const u32 thr = sh_prefix;
  u16* ua = upact + row * DFFN;
  for (int it = 0; it < 4; ++it) {
    int e = it * 2048 + tid * 8;
    uint4 uv = *(const uint4*)(ua + e);
    const u16* up16 = (const u16*)&uv;
    u16 outp[8];
#pragma unroll
    for (int j = 0; j < 8; ++j) {
      u32 bits = sabs[e + j];
      u32 mg = bits & 0x7FFFFFFFu;
      float gg = __builtin_bit_cast(float, bits);
      float prod = (mg >= thr) ? gg * b2f(up16[j]) : 0.0f;
      outp[j] = f2bu(prod);
    }
    uint4 ov;
    ov.x = (u32)outp[0] | ((u32)outp[1] << 16);
    ov.y = (u32)outp[2] | ((u32)outp[3] << 16);
    ov.z = (u32)outp[4] | ((u32)outp[5] << 16);
    ov.w = (u32)outp[6] | ((u32)outp[7] << 16);
    *(uint4*)(ua + e) = ov;
  }
}

// ---------------- launcher ----------------
extern "C" void kernel_launch(void* const* d_in, const int* in_sizes, int n_in,
                              void* d_out, int out_size, void* d_ws, size_t ws_size,
                              hipStream_t stream) {
  const float* hidden = (const float*)d_in[0];
  const float* wq = (const float*)d_in[1];
  const float* wk = (const float*)d_in[2];
  const float* wv = (const float*)d_in[3];
  const float* wo = (const float*)d_in[4];
  const float* ln1 = (const float*)d_in[5];
  const float* ln2 = (const float*)d_in[6];
  const float* wg = (const float*)d_in[7];
  const float* wu = (const float*)d_in[8];
  const float* wd = (const float*)d_in[9];
  float* out = (float*)d_out;
  (void)in_sizes; (void)n_in; (void)out_size;

  // ---- workspace layout (lifetime-aliased, ~196 MB total) ----
  size_t off = 0;
  auto alloc = [&](size_t n) { char* r = (char*)d_ws + off; off += (n + 255) & ~(size_t)255; return r; };
  u16* wq_b = (u16*)alloc((size_t)DMODEL * DMODEL * 2);      // 8 MB
  u16* wk_b = (u16*)alloc((size_t)NKVH * HDIM * DMODEL * 2); // 2 MB
  u16* wv_b = (u16*)alloc((size_t)NKVH * HDIM * DMODEL * 2); // 2 MB
  u16* wo_b = (u16*)alloc((size_t)DMODEL * DMODEL * 2);      // 8 MB
  u16* wg_b = (u16*)alloc((size_t)DFFN * DMODEL * 2);        // 32 MB
  u16* tok  = (u16*)alloc((size_t)MTOK * DMODEL * 2);        // 16 MB: x -> o -> y
  u16* upb  = (u16*)alloc((size_t)MTOK * DFFN * 2);          // 64 MB
  char* S   = alloc((size_t)(MTOK / 2) * DFFN * 4);          // 64 MB shared region
  // phase 1 of S: qb(16) kb(4) vtb(4) wu_b(32)
  u16* qb   = (u16*)S;
  u16* kb   = (u16*)(S + (size_t)MTOK * DMODEL * 2);
  u16* vtb  = (u16*)(S + (size_t)MTOK * DMODEL * 2 + (size_t)MTOK * NKVH * HDIM * 2);
  u16* wu_b = (u16*)(S + (size_t)MTOK * DMODEL * 2 + 2 * (size_t)MTOK * NKVH * HDIM * 2);
  // phase 2 of S: gate half (f32, 2048 x 8192)
  float* gateh = (float*)S;
  // phase 3 of S: wd_b (32 MB)
  u16* wd_b = (u16*)S;
  const size_t needed = off;
  if (ws_size < needed) return;  // clean fast-fail (diagnostic) instead of OOB hang

  auto cvt = [&](const float* src, u16* dst, size_t n) {
    cvt_kernel<<<dim3((unsigned)(n / 1024)), 256, 0, stream>>>(src, dst, (int)n);
  };
  cvt(wq, wq_b, (size_t)DMODEL * DMODEL);
  cvt(wk, wk_b, (size_t)NKVH * HDIM * DMODEL);
  cvt(wv, wv_b, (size_t)NKVH * HDIM * DMODEL);
  cvt(wo, wo_b, (size_t)DMODEL * DMODEL);
  cvt(wg, wg_b, (size_t)DFFN * DMODEL);
  cvt(wu, wu_b, (size_t)DFFN * DMODEL);

  // x = rmsnorm(hidden, ln1)
  rmsnorm_kernel<<<MTOK, 256, 0, stream>>>(hidden, ln1, tok);

  gemm_bt<0><<<dim3(DMODEL / 128, MTOK / 128), 256, 0, stream>>>(
      tok, wq_b, qb, nullptr, MTOK, DMODEL, DMODEL);
  gemm_bt<0><<<dim3(NKVH * HDIM / 128, MTOK / 128), 256, 0, stream>>>(
      tok, wk_b, kb, nullptr, MTOK, NKVH * HDIM, DMODEL);
  gemm_bt<1><<<dim3(NKVH * HDIM / 128, MTOK / 128), 256, 0, stream>>>(
      tok, wv_b, vtb, nullptr, MTOK, NKVH * HDIM, DMODEL);

  // o -> tok (x dead)
  attn_kernel<<<dim3(SEQ / 128, NHEADS, BATCH), 256, 0, stream>>>(qb, kb, vtb, tok);

  // h = hidden + o @ wo^T   -> stored in d_out
  gemm_bt<2><<<dim3(DMODEL / 128, MTOK / 128), 256, 0, stream>>>(
      tok, wo_b, out, hidden, MTOK, DMODEL, DMODEL);

  // y = rmsnorm(h, ln2) -> tok (o dead)
  rmsnorm_kernel<<<MTOK, 256, 0, stream>>>(out, ln2, tok);

  // up = y @ wu^T (bf16) — must complete before S is reused for gate halves
  gemm_bt<0><<<dim3(DFFN / 128, MTOK / 128), 256, 0, stream>>>(
      tok, wu_b, upb, nullptr, MTOK, DFFN, DMODEL);

  // gate halves: silu(y @ wg^T) f32 -> topk+multiply in-place into upb
  for (int half = 0; half < 2; ++half) {
    const u16* yh = tok + (size_t)half * (MTOK / 2) * DMODEL;
    u16* uph = upb + (size_t)half * (MTOK / 2) * DFFN;
    gemm_bt<3><<<dim3(DFFN / 128, (MTOK / 2) / 128), 256, 0, stream>>>(
        yh, wg_b, gateh, nullptr, MTOK / 2, DFFN, DMODEL);
    topk_kernel<<<MTOK / 2, 256, 0, stream>>>(gateh, uph);
  }

  // wd -> bf16 (into S, gate halves dead)
  cvt(wd, wd_b, (size_t)DMODEL * DFFN);

  // out = h + act @ wd^T  (in-place residual over d_out)
  gemm_bt<2><<<dim3(DMODEL / 128, MTOK / 128), 256, 0, stream>>>(
      upb, wd_b, out, out, MTOK, DMODEL, DFFN);
}